// Round 1
// baseline (118.222 us; speedup 1.0000x reference)
//
#include <hip/hip_runtime.h>

#define N_SAMP 1024
#define XD     128
#define HID    256

// ---------------------------------------------------------------------------
// Workspace layout (float indices):
//   [0, 1024)            S       per-i sum of exp(T1[i,j]) over j
//   [1024]               T0sum   sum over i of T1[i,i]  (diagonal == T0 - b2)
//   [2048, 2048+256K)    xpb     x @ W1x + b1   (1024 x 256)
//   [next 256K)          yp      y @ W1y        (1024 x 256)
// Total ~2.01 MB. S/T0sum must be zeroed each launch (ws is poisoned 0xAA).
// ---------------------------------------------------------------------------

// Kernel 1: the two small GEMMs. 256 blocks x 256 threads; each block does 4
// rows of both x and y; thread k owns hidden unit k (coalesced W1 reads).
// x/y addresses are thread-uniform -> compiler emits s_load (constant cache).
__global__ __launch_bounds__(256) void gemm_xy(
    const float* __restrict__ x, const float* __restrict__ y,
    const float* __restrict__ W1, const float* __restrict__ b1,
    float* __restrict__ xpb, float* __restrict__ yp)
{
    const int k  = threadIdx.x;        // hidden unit 0..255
    const int r0 = blockIdx.x * 4;     // 4 rows per block

    float ax0 = 0.f, ax1 = 0.f, ax2 = 0.f, ax3 = 0.f;
    float ay0 = 0.f, ay1 = 0.f, ay2 = 0.f, ay3 = 0.f;

    #pragma unroll 4
    for (int d = 0; d < XD; ++d) {
        const float wx = W1[d * HID + k];            // coalesced over k
        const float wy = W1[(XD + d) * HID + k];
        ax0 = fmaf(x[(r0 + 0) * XD + d], wx, ax0);   // uniform -> s_load
        ax1 = fmaf(x[(r0 + 1) * XD + d], wx, ax1);
        ax2 = fmaf(x[(r0 + 2) * XD + d], wx, ax2);
        ax3 = fmaf(x[(r0 + 3) * XD + d], wx, ax3);
        ay0 = fmaf(y[(r0 + 0) * XD + d], wy, ay0);
        ay1 = fmaf(y[(r0 + 1) * XD + d], wy, ay1);
        ay2 = fmaf(y[(r0 + 2) * XD + d], wy, ay2);
        ay3 = fmaf(y[(r0 + 3) * XD + d], wy, ay3);
    }

    const float bk = b1[k];
    xpb[(r0 + 0) * HID + k] = ax0 + bk;
    xpb[(r0 + 1) * HID + k] = ax1 + bk;
    xpb[(r0 + 2) * HID + k] = ax2 + bk;
    xpb[(r0 + 3) * HID + k] = ax3 + bk;
    yp [(r0 + 0) * HID + k] = ay0;
    yp [(r0 + 1) * HID + k] = ay1;
    yp [(r0 + 2) * HID + k] = ay2;
    yp [(r0 + 3) * HID + k] = ay3;
}

// Kernel 2: pairwise relu-dot + online exp accumulation.
// Grid 64x64 blocks; block (bj,bi) handles the 16x16 (i,j) tile. One pair per
// thread, k-loop of 256 via float4 LDS reads. LDS rows padded to stride 260
// (260 % 32 == 4 -> worst case 2-way bank aliasing, which is free on gfx950).
// W2 reads are loop-uniform -> scalarized to s_load, no LDS traffic.
__global__ __launch_bounds__(256) void pair_lse(
    const float* __restrict__ yp, const float* __restrict__ xpb,
    const float* __restrict__ W2,
    float* __restrict__ S, float* __restrict__ T0sum)
{
    const int STRIDE = 260;
    __shared__ float ys[16 * 260];
    __shared__ float xs[16 * 260];

    const int tid = threadIdx.x;
    const int bi  = blockIdx.y;
    const int bj  = blockIdx.x;

    // Stage both 16x256 tiles, float4-coalesced (4 iters x 16 B per thread).
    for (int idx = tid * 4; idx < 16 * 256; idx += 1024) {
        const int r = idx >> 8, c = idx & 255;
        *(float4*)&ys[r * STRIDE + c] = *(const float4*)&yp [(bi * 16 + r) * HID + c];
        *(float4*)&xs[r * STRIDE + c] = *(const float4*)&xpb[(bj * 16 + r) * HID + c];
    }
    __syncthreads();

    const int ti = tid >> 4;        // i within tile
    const int tj = tid & 15;        // j within tile
    const float* yrow = &ys[ti * STRIDE];
    const float* xrow = &xs[tj * STRIDE];

    float acc = 0.f;
    #pragma unroll 8
    for (int c = 0; c < HID; c += 4) {
        const float4 a = *(const float4*)&yrow[c];
        const float4 b = *(const float4*)&xrow[c];
        const float4 w = *(const float4*)&W2[c];      // uniform -> s_load
        acc = fmaf(fmaxf(a.x + b.x, 0.f), w.x, acc);
        acc = fmaf(fmaxf(a.y + b.y, 0.f), w.y, acc);
        acc = fmaf(fmaxf(a.z + b.z, 0.f), w.z, acc);
        acc = fmaf(fmaxf(a.w + b.w, 0.f), w.w, acc);
    }

    // T1[i,j] sans b2. |acc| is small (~N(0,0.5)) so exp without max-shift
    // is safe in f32; b2 is reattached (and cancels) in finalize.
    float e = __expf(acc);
    #pragma unroll
    for (int off = 8; off; off >>= 1) e += __shfl_xor(e, off, 16);
    const int gi = bi * 16 + ti;
    if (tj == 0) atomicAdd(&S[gi], e);

    // Diagonal contribution (T0): reduce within each wave, 4 atomics/block.
    if (bi == bj) {
        float dv = (ti == tj) ? acc : 0.f;
        #pragma unroll
        for (int off = 32; off; off >>= 1) dv += __shfl_xor(dv, off, 64);
        if ((tid & 63) == 0) atomicAdd(T0sum, dv);
    }
}

// Kernel 3: lse[i] = log(S[i]); combine means. Single block.
__global__ __launch_bounds__(256) void finalize(
    const float* __restrict__ S, const float* __restrict__ T0sum,
    const float* __restrict__ b2, float* __restrict__ out)
{
    __shared__ float red[4];
    const int tid = threadIdx.x;

    float ls = 0.f;
    for (int i = tid; i < N_SAMP; i += 256) ls += logf(S[i]);
    #pragma unroll
    for (int off = 32; off; off >>= 1) ls += __shfl_xor(ls, off, 64);
    if ((tid & 63) == 0) red[tid >> 6] = ls;
    __syncthreads();

    if (tid == 0) {
        const float lse_sum = red[0] + red[1] + red[2] + red[3];
        const float t0_mean  = T0sum[0] / (float)N_SAMP + b2[0];
        const float lse_mean = lse_sum / (float)N_SAMP + b2[0] - logf((float)N_SAMP);
        out[0] = t0_mean - lse_mean;
    }
}

extern "C" void kernel_launch(void* const* d_in, const int* in_sizes, int n_in,
                              void* d_out, int out_size, void* d_ws, size_t ws_size,
                              hipStream_t stream)
{
    const float* x  = (const float*)d_in[0];
    const float* y  = (const float*)d_in[1];
    const float* W1 = (const float*)d_in[2];
    const float* b1 = (const float*)d_in[3];
    const float* W2 = (const float*)d_in[4];
    const float* b2 = (const float*)d_in[5];

    float* ws   = (float*)d_ws;
    float* S    = ws;                          // 1024 floats
    float* T0s  = ws + 1024;                   // 1 float
    float* xpb  = ws + 2048;                   // 1024*256
    float* yp   = ws + 2048 + N_SAMP * HID;    // 1024*256

    // Zero the accumulators (ws is re-poisoned to 0xAA before every launch).
    hipMemsetAsync(d_ws, 0, (1024 + 1) * sizeof(float), stream);

    gemm_xy <<<dim3(N_SAMP / 4), dim3(256), 0, stream>>>(x, y, W1, b1, xpb, yp);
    pair_lse<<<dim3(64, 64),     dim3(256), 0, stream>>>(yp, xpb, W2, S, T0s);
    finalize<<<dim3(1),          dim3(256), 0, stream>>>(S, T0s, b2, (float*)d_out);
}